// Round 5
// baseline (304.289 us; speedup 1.0000x reference)
//
#include <hip/hip_runtime.h>
#include <hip/hip_bf16.h>
#include <math.h>

#define B_    64
#define TQ    32
#define TD    4096
#define HDIM  300
#define NB    29      // histogram bins
#define NFEAT 30      // 29 bins + exact-match feature
#define DTILE 256
#define NCHUNK 16     // TD / DTILE
#define HC    20      // h chunk size
#define NHC   15      // HDIM / HC
#define NF4   5       // HC / 4 float4 per row-chunk
#define THREADS 256

// bin upper bounds: jnp.linspace(-1,1,30)[1:], ub[k] = -1 + 2(k+1)/29
__device__ __forceinline__ float ubf(int k) {
    return (float)(-1.0 + (2.0 * (double)(k + 1)) / 29.0);
}

// bin one similarity value into the per-block LDS histogram
__device__ __forceinline__ void bin_one(float sim, unsigned* s_hist, int q) {
    if (sim > 0.999f && sim < 1.001f) {
        // only exact token matches land here; true sim < 1.0 strictly -> bin 28
        atomicAdd(&s_hist[q * NFEAT + 28], 1u);
        atomicAdd(&s_hist[q * NFEAT + 29], 1u);   // exact-match feature
    } else {
        int idx = (int)((sim + 1.0f) * 14.5f);    // guess, then exact fixup
        idx = idx < 0 ? 0 : (idx > NB ? NB : idx);
        while (idx < NB && sim >= ubf(idx)) ++idx;
        while (idx > 0 && sim < ubf(idx - 1)) --idx;
        if (idx < NB) atomicAdd(&s_hist[q * NFEAT + idx], 1u);
    }
}

// ---------------- main: fused norms + sim GEMM + histogram ----------------
// 256 threads = 4 waves; tile 32q x 256d; LDS ~28.5 KB -> 4-5 blocks/CU.
// Wave w computes q rows w*8..w*8+7 x all 256 d; lane owns d = lane*4..+3.
// Staging: thread t owns d-row t for ALL chunks (5 float4/chunk, exact reg norm);
// threads<32 also own q-row t. Next chunk's rows prefetched into regs (T14).
// launch_bounds(256,4): 4 blocks/CU (CUDA-semantics on this hipcc, r3/r4 evidence)
// -> 128-VGPR cap under either interpretation.
__global__ __launch_bounds__(THREADS, 4) void k_main(
        const int* __restrict__ sent, const int* __restrict__ qsent,
        const float* __restrict__ emb, unsigned* __restrict__ ghist) {
    __shared__ __align__(16) float dxT[HC][DTILE];   // 20 KB transposed tile
    __shared__ __align__(16) float qxT[HC][TQ];      // 2.5 KB
    __shared__ int      toks[DTILE];
    __shared__ int      qtk[TQ];
    __shared__ float    s_iq[TQ];
    __shared__ float    s_id[DTILE];
    __shared__ unsigned s_hist[TQ * NFEAT];

    const int b    = blockIdx.x >> 4;
    const int d0   = (blockIdx.x & 15) * DTILE;
    const int tid  = threadIdx.x;
    const int wid  = tid >> 6;
    const int lane = tid & 63;

    toks[tid] = sent[b * TD + d0 + tid];
    if (tid < TQ) qtk[tid] = qsent[b * TQ + tid];
    __syncthreads();

    // staging roles: thread t owns d-row t (and q-row t if t<32)
    const float* dptr = emb + (size_t)toks[tid] * HDIM;
    const bool   doq  = (tid < TQ);
    const float* qptr = emb + (size_t)(doq ? qtk[tid] : 0) * HDIM;

    float nd = 0.f, nq = 0.f;                // exact per-row norm accumulators

    // compute roles
    const int q0  = wid * 8;
    const int myd = lane * 4;

    float acc[8][4];
#pragma unroll
    for (int qi = 0; qi < 8; ++qi)
#pragma unroll
        for (int di = 0; di < 4; ++di) acc[qi][di] = 0.f;

    // ---- prefetch chunk 0 rows into registers
    float4 dreg[NF4], qv[NF4];
#pragma unroll
    for (int jf = 0; jf < NF4; ++jf) dreg[jf] = *(const float4*)(dptr + jf * 4);
    if (doq) {
#pragma unroll
        for (int jf = 0; jf < NF4; ++jf) qv[jf] = *(const float4*)(qptr + jf * 4);
    }

    for (int hc = 0; hc < NHC; ++hc) {
        // ---- write prefetched rows: column writes, lanes = consecutive rows (2-way, free)
#pragma unroll
        for (int jf = 0; jf < NF4; ++jf) {
            float4 v = dreg[jf];
            const int h = jf * 4;
            dxT[h + 0][tid] = v.x; dxT[h + 1][tid] = v.y;
            dxT[h + 2][tid] = v.z; dxT[h + 3][tid] = v.w;
            nd = fmaf(v.x, v.x, nd); nd = fmaf(v.y, v.y, nd);
            nd = fmaf(v.z, v.z, nd); nd = fmaf(v.w, v.w, nd);
        }
        if (doq) {
#pragma unroll
            for (int jf = 0; jf < NF4; ++jf) {
                float4 v = qv[jf];
                const int h = jf * 4;
                qxT[h + 0][tid] = v.x; qxT[h + 1][tid] = v.y;
                qxT[h + 2][tid] = v.z; qxT[h + 3][tid] = v.w;
                nq = fmaf(v.x, v.x, nq); nq = fmaf(v.y, v.y, nq);
                nq = fmaf(v.z, v.z, nq); nq = fmaf(v.w, v.w, nq);
            }
        }
        // ---- prefetch next chunk (in flight across the compute phase)
        if (hc + 1 < NHC) {
            const float* p = dptr + (hc + 1) * HC;
#pragma unroll
            for (int jf = 0; jf < NF4; ++jf) dreg[jf] = *(const float4*)(p + jf * 4);
            if (doq) {
                const float* pq = qptr + (hc + 1) * HC;
#pragma unroll
                for (int jf = 0; jf < NF4; ++jf) qv[jf] = *(const float4*)(pq + jf * 4);
            }
        }
        __syncthreads();

        // ---- compute: per h: 1 lane-contiguous b128 (dx) + 2 uniform b128 (qx), 32 FMA
#pragma unroll
        for (int h = 0; h < HC; ++h) {
            float4 dv = *(const float4*)&dxT[h][myd];
            float4 a  = *(const float4*)&qxT[h][q0];
            float4 c  = *(const float4*)&qxT[h][q0 + 4];
            acc[0][0] = fmaf(a.x, dv.x, acc[0][0]); acc[0][1] = fmaf(a.x, dv.y, acc[0][1]);
            acc[0][2] = fmaf(a.x, dv.z, acc[0][2]); acc[0][3] = fmaf(a.x, dv.w, acc[0][3]);
            acc[1][0] = fmaf(a.y, dv.x, acc[1][0]); acc[1][1] = fmaf(a.y, dv.y, acc[1][1]);
            acc[1][2] = fmaf(a.y, dv.z, acc[1][2]); acc[1][3] = fmaf(a.y, dv.w, acc[1][3]);
            acc[2][0] = fmaf(a.z, dv.x, acc[2][0]); acc[2][1] = fmaf(a.z, dv.y, acc[2][1]);
            acc[2][2] = fmaf(a.z, dv.z, acc[2][2]); acc[2][3] = fmaf(a.z, dv.w, acc[2][3]);
            acc[3][0] = fmaf(a.w, dv.x, acc[3][0]); acc[3][1] = fmaf(a.w, dv.y, acc[3][1]);
            acc[3][2] = fmaf(a.w, dv.z, acc[3][2]); acc[3][3] = fmaf(a.w, dv.w, acc[3][3]);
            acc[4][0] = fmaf(c.x, dv.x, acc[4][0]); acc[4][1] = fmaf(c.x, dv.y, acc[4][1]);
            acc[4][2] = fmaf(c.x, dv.z, acc[4][2]); acc[4][3] = fmaf(c.x, dv.w, acc[4][3]);
            acc[5][0] = fmaf(c.y, dv.x, acc[5][0]); acc[5][1] = fmaf(c.y, dv.y, acc[5][1]);
            acc[5][2] = fmaf(c.y, dv.z, acc[5][2]); acc[5][3] = fmaf(c.y, dv.w, acc[5][3]);
            acc[6][0] = fmaf(c.z, dv.x, acc[6][0]); acc[6][1] = fmaf(c.z, dv.y, acc[6][1]);
            acc[6][2] = fmaf(c.z, dv.z, acc[6][2]); acc[6][3] = fmaf(c.z, dv.w, acc[6][3]);
            acc[7][0] = fmaf(c.w, dv.x, acc[7][0]); acc[7][1] = fmaf(c.w, dv.y, acc[7][1]);
            acc[7][2] = fmaf(c.w, dv.z, acc[7][2]); acc[7][3] = fmaf(c.w, dv.w, acc[7][3]);
        }
        __syncthreads();   // before next chunk overwrites dxT/qxT
    }

    // ---- finalize norms (exact single-register sums), init hist
    s_id[tid] = 1.0f / (sqrtf(nd + 1e-7f) + 1e-7f);
    if (doq) s_iq[tid] = 1.0f / (sqrtf(nq + 1e-7f) + 1e-7f);
    for (int i = tid; i < TQ * NFEAT; i += THREADS) s_hist[i] = 0u;
    __syncthreads();

    // ---- epilogue: sim -> bins (fully unrolled: acc stays in registers)
    {
        float id[4];
        bool  vd[4];
#pragma unroll
        for (int di = 0; di < 4; ++di) {
            id[di] = s_id[myd + di];
            vd[di] = (toks[myd + di] != 0);   // masked doc: +1e7 -> dropped everywhere
        }
#pragma unroll
        for (int qi = 0; qi < 8; ++qi) {
            const int q = q0 + qi;
            const float iq = s_iq[q];
#pragma unroll
            for (int di = 0; di < 4; ++di)
                if (vd[di]) bin_one(acc[qi][di] * iq * id[di], s_hist, q);
        }
    }
    __syncthreads();
    for (int i = tid; i < TQ * NFEAT; i += THREADS) {
        unsigned v = s_hist[i];
        if (v) atomicAdd(&ghist[b * TQ * NFEAT + i], v);
    }
}

// ---------------- finish: log + MLP + gate softmax ----------------
__global__ void k_finish(const unsigned* __restrict__ ghist,
                         const int* __restrict__ qsent, const float* __restrict__ idf,
                         const float* __restrict__ w1, const float* __restrict__ b1,
                         const float* __restrict__ w2, const float* __restrict__ b2,
                         const float* __restrict__ gw, const float* __restrict__ ow,
                         const float* __restrict__ ob, float* __restrict__ out) {
    int b = blockIdx.x;
    int lane = threadIdx.x;   // 64 threads, lanes 0..31 active
    float ffw = 0.f;
    float logit = -3.0e38f;
    if (lane < TQ) {
        const unsigned* h = ghist + (b * TQ + lane) * NFEAT;
        float f[NFEAT];
        for (int k = 0; k < NFEAT; ++k) f[k] = logf((float)h[k] + 1.0f);
        float s2 = b2[0];
        for (int n = 0; n < 5; ++n) {
            float s = b1[n];
            for (int k = 0; k < NFEAT; ++k) s = fmaf(f[k], w1[k * 5 + n], s);
            s2 = fmaf(tanhf(s), w2[n], s2);
        }
        ffw = tanhf(s2);
        int qt = qsent[b * TQ + lane];
        logit = idf[b * TQ + lane] * gw[0] + (qt == 0 ? -1e7f : 0.f);
    }
    float m = logit;
#pragma unroll
    for (int t = 1; t < 64; t <<= 1) m = fmaxf(m, __shfl_xor(m, t, 64));
    float e = expf(logit - m);            // inactive lanes -> exp(-inf) = 0
    float se = e, sw = e * ffw;
#pragma unroll
    for (int t = 1; t < 64; t <<= 1) {
        se += __shfl_xor(se, t, 64);
        sw += __shfl_xor(sw, t, 64);
    }
    if (lane == 0) out[b] = (sw / se) * ow[0] + ob[0];
}

extern "C" void kernel_launch(void* const* d_in, const int* in_sizes, int n_in,
                              void* d_out, int out_size, void* d_ws, size_t ws_size,
                              hipStream_t stream) {
    const int*   sent  = (const int*)d_in[0];
    const int*   qsent = (const int*)d_in[1];
    const float* idf   = (const float*)d_in[2];
    const float* emb   = (const float*)d_in[3];
    const float* w1    = (const float*)d_in[4];
    const float* b1    = (const float*)d_in[5];
    const float* w2    = (const float*)d_in[6];
    const float* b2    = (const float*)d_in[7];
    const float* gw    = (const float*)d_in[8];
    const float* ow    = (const float*)d_in[9];
    const float* ob    = (const float*)d_in[10];
    float* out = (float*)d_out;

    unsigned* ghist = (unsigned*)d_ws;                 // 64*32*30 u32 = 240 KB

    hipMemsetAsync(ghist, 0, (size_t)B_ * TQ * NFEAT * 4, stream);
    k_main<<<B_ * NCHUNK, THREADS, 0, stream>>>(sent, qsent, emb, ghist);
    k_finish<<<B_, 64, 0, stream>>>(ghist, qsent, idf, w1, b1, w2, b2, gw, ow, ob, out);
}

// Round 6
// 150.348 us; speedup vs baseline: 2.0239x; 2.0239x over previous
//
#include <hip/hip_runtime.h>
#include <hip/hip_bf16.h>
#include <math.h>

#define B_    64
#define TQ    32
#define TD    4096
#define HDIM  300
#define NB    29      // histogram bins
#define NFEAT 30      // 29 bins + exact-match feature
#define DTILE 256
#define NCHUNK 16     // TD / DTILE
#define HC    20      // h chunk size
#define NHC   15      // HDIM / HC
#define NF4   5       // HC / 4 float4 per row-chunk
#define THREADS 256

// bin upper bounds: jnp.linspace(-1,1,30)[1:], ub[k] = -1 + 2(k+1)/29
__device__ __forceinline__ float ubf(int k) {
    return (float)(-1.0 + (2.0 * (double)(k + 1)) / 29.0);
}

// bin one similarity value into the per-block LDS histogram
__device__ __forceinline__ void bin_one(float sim, unsigned* s_hist, int q) {
    if (sim > 0.999f && sim < 1.001f) {
        // only exact token matches land here; true sim < 1.0 strictly -> bin 28
        atomicAdd(&s_hist[q * NFEAT + 28], 1u);
        atomicAdd(&s_hist[q * NFEAT + 29], 1u);   // exact-match feature
    } else {
        int idx = (int)((sim + 1.0f) * 14.5f);    // guess, then exact fixup
        idx = idx < 0 ? 0 : (idx > NB ? NB : idx);
        while (idx < NB && sim >= ubf(idx)) ++idx;
        while (idx > 0 && sim < ubf(idx - 1)) --idx;
        if (idx < NB) atomicAdd(&s_hist[q * NFEAT + idx], 1u);
    }
}

// ---------------- main: fused norms + sim GEMM + histogram ----------------
// 256 threads = 4 waves; tile 32q x 256d; LDS ~28.5 KB.
// Wave w computes q rows w*8..w*8+7 x all 256 d; lane owns d = lane*4..+3.
// Staging: thread t owns d-row t for ALL chunks (5 float4/chunk, exact reg norm),
// with next-chunk register prefetch (T14); threads<32 stage q-row t directly
// (no prefetch -> saves 20 VGPR; latency covered by other resident blocks).
// VGPR-cap empirics on this hipcc: cap = 256/(2nd launch_bounds arg):
//   (512,4)->64 [r3 spills], (512,2)->128 [r4 ok], (256,4)->64 [r5 spills].
// So (256,2) -> 128-VGPR cap; need ~85-100 -> no spills, 16 waves/CU.
__global__ __launch_bounds__(THREADS, 2) void k_main(
        const int* __restrict__ sent, const int* __restrict__ qsent,
        const float* __restrict__ emb, unsigned* __restrict__ ghist) {
    __shared__ __align__(16) float dxT[HC][DTILE];   // 20 KB transposed tile
    __shared__ __align__(16) float qxT[HC][TQ];      // 2.5 KB
    __shared__ int      toks[DTILE];
    __shared__ int      qtk[TQ];
    __shared__ float    s_iq[TQ];
    __shared__ float    s_id[DTILE];
    __shared__ unsigned s_hist[TQ * NFEAT];

    const int b    = blockIdx.x >> 4;
    const int d0   = (blockIdx.x & 15) * DTILE;
    const int tid  = threadIdx.x;
    const int wid  = tid >> 6;
    const int lane = tid & 63;

    toks[tid] = sent[b * TD + d0 + tid];
    if (tid < TQ) qtk[tid] = qsent[b * TQ + tid];
    __syncthreads();

    // staging roles: thread t owns d-row t (and q-row t if t<32)
    const float* dptr = emb + (size_t)toks[tid] * HDIM;
    const bool   doq  = (tid < TQ);
    const float* qptr = emb + (size_t)(doq ? qtk[tid] : 0) * HDIM;

    float nd = 0.f, nq = 0.f;                // exact per-row norm accumulators

    // compute roles
    const int q0  = wid * 8;
    const int myd = lane * 4;

    float acc[8][4];
#pragma unroll
    for (int qi = 0; qi < 8; ++qi)
#pragma unroll
        for (int di = 0; di < 4; ++di) acc[qi][di] = 0.f;

    // ---- prefetch chunk 0 d-rows into registers
    float4 dreg[NF4];
#pragma unroll
    for (int jf = 0; jf < NF4; ++jf) dreg[jf] = *(const float4*)(dptr + jf * 4);

    for (int hc = 0; hc < NHC; ++hc) {
        // ---- q rows: direct load (issue first; latency hides under d writes below)
        float4 qv0, qv1, qv2, qv3, qv4;
        if (doq) {
            const float* pq = qptr + hc * HC;
            qv0 = *(const float4*)(pq);      qv1 = *(const float4*)(pq + 4);
            qv2 = *(const float4*)(pq + 8);  qv3 = *(const float4*)(pq + 12);
            qv4 = *(const float4*)(pq + 16);
        }

        // ---- write prefetched d-rows: column writes, lanes = consecutive rows (2-way, free)
#pragma unroll
        for (int jf = 0; jf < NF4; ++jf) {
            float4 v = dreg[jf];
            const int h = jf * 4;
            dxT[h + 0][tid] = v.x; dxT[h + 1][tid] = v.y;
            dxT[h + 2][tid] = v.z; dxT[h + 3][tid] = v.w;
            nd = fmaf(v.x, v.x, nd); nd = fmaf(v.y, v.y, nd);
            nd = fmaf(v.z, v.z, nd); nd = fmaf(v.w, v.w, nd);
        }
        // ---- prefetch next chunk's d-rows (in flight across the compute phase)
        if (hc + 1 < NHC) {
            const float* p = dptr + (hc + 1) * HC;
#pragma unroll
            for (int jf = 0; jf < NF4; ++jf) dreg[jf] = *(const float4*)(p + jf * 4);
        }
        // ---- write q rows
        if (doq) {
            float4 v;
            v = qv0; qxT[0][tid] = v.x; qxT[1][tid] = v.y; qxT[2][tid] = v.z; qxT[3][tid] = v.w;
            nq = fmaf(v.x, v.x, nq); nq = fmaf(v.y, v.y, nq); nq = fmaf(v.z, v.z, nq); nq = fmaf(v.w, v.w, nq);
            v = qv1; qxT[4][tid] = v.x; qxT[5][tid] = v.y; qxT[6][tid] = v.z; qxT[7][tid] = v.w;
            nq = fmaf(v.x, v.x, nq); nq = fmaf(v.y, v.y, nq); nq = fmaf(v.z, v.z, nq); nq = fmaf(v.w, v.w, nq);
            v = qv2; qxT[8][tid] = v.x; qxT[9][tid] = v.y; qxT[10][tid] = v.z; qxT[11][tid] = v.w;
            nq = fmaf(v.x, v.x, nq); nq = fmaf(v.y, v.y, nq); nq = fmaf(v.z, v.z, nq); nq = fmaf(v.w, v.w, nq);
            v = qv3; qxT[12][tid] = v.x; qxT[13][tid] = v.y; qxT[14][tid] = v.z; qxT[15][tid] = v.w;
            nq = fmaf(v.x, v.x, nq); nq = fmaf(v.y, v.y, nq); nq = fmaf(v.z, v.z, nq); nq = fmaf(v.w, v.w, nq);
            v = qv4; qxT[16][tid] = v.x; qxT[17][tid] = v.y; qxT[18][tid] = v.z; qxT[19][tid] = v.w;
            nq = fmaf(v.x, v.x, nq); nq = fmaf(v.y, v.y, nq); nq = fmaf(v.z, v.z, nq); nq = fmaf(v.w, v.w, nq);
        }
        __syncthreads();

        // ---- compute: per h: 1 lane-contiguous b128 (dx) + 2 uniform b128 (qx), 32 FMA
#pragma unroll
        for (int h = 0; h < HC; ++h) {
            float4 dv = *(const float4*)&dxT[h][myd];
            float4 a  = *(const float4*)&qxT[h][q0];
            float4 c  = *(const float4*)&qxT[h][q0 + 4];
            acc[0][0] = fmaf(a.x, dv.x, acc[0][0]); acc[0][1] = fmaf(a.x, dv.y, acc[0][1]);
            acc[0][2] = fmaf(a.x, dv.z, acc[0][2]); acc[0][3] = fmaf(a.x, dv.w, acc[0][3]);
            acc[1][0] = fmaf(a.y, dv.x, acc[1][0]); acc[1][1] = fmaf(a.y, dv.y, acc[1][1]);
            acc[1][2] = fmaf(a.y, dv.z, acc[1][2]); acc[1][3] = fmaf(a.y, dv.w, acc[1][3]);
            acc[2][0] = fmaf(a.z, dv.x, acc[2][0]); acc[2][1] = fmaf(a.z, dv.y, acc[2][1]);
            acc[2][2] = fmaf(a.z, dv.z, acc[2][2]); acc[2][3] = fmaf(a.z, dv.w, acc[2][3]);
            acc[3][0] = fmaf(a.w, dv.x, acc[3][0]); acc[3][1] = fmaf(a.w, dv.y, acc[3][1]);
            acc[3][2] = fmaf(a.w, dv.z, acc[3][2]); acc[3][3] = fmaf(a.w, dv.w, acc[3][3]);
            acc[4][0] = fmaf(c.x, dv.x, acc[4][0]); acc[4][1] = fmaf(c.x, dv.y, acc[4][1]);
            acc[4][2] = fmaf(c.x, dv.z, acc[4][2]); acc[4][3] = fmaf(c.x, dv.w, acc[4][3]);
            acc[5][0] = fmaf(c.y, dv.x, acc[5][0]); acc[5][1] = fmaf(c.y, dv.y, acc[5][1]);
            acc[5][2] = fmaf(c.y, dv.z, acc[5][2]); acc[5][3] = fmaf(c.y, dv.w, acc[5][3]);
            acc[6][0] = fmaf(c.z, dv.x, acc[6][0]); acc[6][1] = fmaf(c.z, dv.y, acc[6][1]);
            acc[6][2] = fmaf(c.z, dv.z, acc[6][2]); acc[6][3] = fmaf(c.z, dv.w, acc[6][3]);
            acc[7][0] = fmaf(c.w, dv.x, acc[7][0]); acc[7][1] = fmaf(c.w, dv.y, acc[7][1]);
            acc[7][2] = fmaf(c.w, dv.z, acc[7][2]); acc[7][3] = fmaf(c.w, dv.w, acc[7][3]);
        }
        __syncthreads();   // before next chunk overwrites dxT/qxT
    }

    // ---- finalize norms (exact single-register sums), init hist
    s_id[tid] = 1.0f / (sqrtf(nd + 1e-7f) + 1e-7f);
    if (doq) s_iq[tid] = 1.0f / (sqrtf(nq + 1e-7f) + 1e-7f);
    for (int i = tid; i < TQ * NFEAT; i += THREADS) s_hist[i] = 0u;
    __syncthreads();

    // ---- epilogue: sim -> bins (fully unrolled: acc stays in registers)
    {
        float id[4];
        bool  vd[4];
#pragma unroll
        for (int di = 0; di < 4; ++di) {
            id[di] = s_id[myd + di];
            vd[di] = (toks[myd + di] != 0);   // masked doc: +1e7 -> dropped everywhere
        }
#pragma unroll
        for (int qi = 0; qi < 8; ++qi) {
            const int q = q0 + qi;
            const float iq = s_iq[q];
#pragma unroll
            for (int di = 0; di < 4; ++di)
                if (vd[di]) bin_one(acc[qi][di] * iq * id[di], s_hist, q);
        }
    }
    __syncthreads();
    for (int i = tid; i < TQ * NFEAT; i += THREADS) {
        unsigned v = s_hist[i];
        if (v) atomicAdd(&ghist[b * TQ * NFEAT + i], v);
    }
}

// ---------------- finish: log + MLP + gate softmax ----------------
__global__ void k_finish(const unsigned* __restrict__ ghist,
                         const int* __restrict__ qsent, const float* __restrict__ idf,
                         const float* __restrict__ w1, const float* __restrict__ b1,
                         const float* __restrict__ w2, const float* __restrict__ b2,
                         const float* __restrict__ gw, const float* __restrict__ ow,
                         const float* __restrict__ ob, float* __restrict__ out) {
    int b = blockIdx.x;
    int lane = threadIdx.x;   // 64 threads, lanes 0..31 active
    float ffw = 0.f;
    float logit = -3.0e38f;
    if (lane < TQ) {
        const unsigned* h = ghist + (b * TQ + lane) * NFEAT;
        float f[NFEAT];
        for (int k = 0; k < NFEAT; ++k) f[k] = logf((float)h[k] + 1.0f);
        float s2 = b2[0];
        for (int n = 0; n < 5; ++n) {
            float s = b1[n];
            for (int k = 0; k < NFEAT; ++k) s = fmaf(f[k], w1[k * 5 + n], s);
            s2 = fmaf(tanhf(s), w2[n], s2);
        }
        ffw = tanhf(s2);
        int qt = qsent[b * TQ + lane];
        logit = idf[b * TQ + lane] * gw[0] + (qt == 0 ? -1e7f : 0.f);
    }
    float m = logit;
#pragma unroll
    for (int t = 1; t < 64; t <<= 1) m = fmaxf(m, __shfl_xor(m, t, 64));
    float e = expf(logit - m);            // inactive lanes -> exp(-inf) = 0
    float se = e, sw = e * ffw;
#pragma unroll
    for (int t = 1; t < 64; t <<= 1) {
        se += __shfl_xor(se, t, 64);
        sw += __shfl_xor(sw, t, 64);
    }
    if (lane == 0) out[b] = (sw / se) * ow[0] + ob[0];
}

extern "C" void kernel_launch(void* const* d_in, const int* in_sizes, int n_in,
                              void* d_out, int out_size, void* d_ws, size_t ws_size,
                              hipStream_t stream) {
    const int*   sent  = (const int*)d_in[0];
    const int*   qsent = (const int*)d_in[1];
    const float* idf   = (const float*)d_in[2];
    const float* emb   = (const float*)d_in[3];
    const float* w1    = (const float*)d_in[4];
    const float* b1    = (const float*)d_in[5];
    const float* w2    = (const float*)d_in[6];
    const float* b2    = (const float*)d_in[7];
    const float* gw    = (const float*)d_in[8];
    const float* ow    = (const float*)d_in[9];
    const float* ob    = (const float*)d_in[10];
    float* out = (float*)d_out;

    unsigned* ghist = (unsigned*)d_ws;                 // 64*32*30 u32 = 240 KB

    hipMemsetAsync(ghist, 0, (size_t)B_ * TQ * NFEAT * 4, stream);
    k_main<<<B_ * NCHUNK, THREADS, 0, stream>>>(sent, qsent, emb, ghist);
    k_finish<<<B_, 64, 0, stream>>>(ghist, qsent, idf, w1, b1, w2, b2, gw, ow, ob, out);
}

// Round 7
// 146.288 us; speedup vs baseline: 2.0801x; 1.0278x over previous
//
#include <hip/hip_runtime.h>
#include <hip/hip_bf16.h>
#include <math.h>

#define B_    64
#define TQ    32
#define TD    4096
#define HDIM  300
#define NB    29      // histogram bins
#define NFEAT 30      // 29 bins + exact-match feature
#define DTILE 256
#define NCHUNK 16     // TD / DTILE
#define HC    20      // h chunk size
#define NHC   15      // HDIM / HC
#define NF4   5       // HC / 4 float4 per row-chunk
#define THREADS 256

typedef float v2f __attribute__((ext_vector_type(2)));
#define FMA2(a, b, c) __builtin_elementwise_fma((a), (b), (c))

// bin upper bounds: jnp.linspace(-1,1,30)[1:], ub[k] = -1 + 2(k+1)/29
__device__ __forceinline__ float ubf(int k) {
    return (float)(-1.0 + (2.0 * (double)(k + 1)) / 29.0);
}

// bin one similarity value into the per-block LDS histogram
__device__ __forceinline__ void bin_one(float sim, unsigned* s_hist, int q) {
    if (sim > 0.999f && sim < 1.001f) {
        // only exact token matches land here; true sim < 1.0 strictly -> bin 28
        atomicAdd(&s_hist[q * NFEAT + 28], 1u);
        atomicAdd(&s_hist[q * NFEAT + 29], 1u);   // exact-match feature
    } else {
        int idx = (int)((sim + 1.0f) * 14.5f);    // guess, then exact fixup
        idx = idx < 0 ? 0 : (idx > NB ? NB : idx);
        while (idx < NB && sim >= ubf(idx)) ++idx;
        while (idx > 0 && sim < ubf(idx - 1)) --idx;
        if (idx < NB) atomicAdd(&s_hist[q * NFEAT + idx], 1u);
    }
}

// ---------------- main: fused norms + sim GEMM + histogram ----------------
// 256 threads = 4 waves; tile 32q x 256d; LDS ~28.5 KB.
// Wave w computes q rows w*8..w*8+7 x all 256 d; lane owns d = lane*4..+3.
// Inner loop uses v_pk_fma_f32 (packed dual fp32 FMA) over q-pairs: the qx
// float4 supplies {x,y}/{z,w} as free subregister v2f pairs; dx is splatted.
// Arithmetic order per acc element is IDENTICAL to the scalar version.
// Staging: thread t owns d-row t (T14 reg prefetch); threads<32 stage q-row t.
// VGPR-cap empirics on this hipcc: (512,4)/(256,4)->64-cap [spills r3/r5],
// (THREADS,2) -> >=128 cap [r4/r6 ok]. Keep (THREADS,2).
__global__ __launch_bounds__(THREADS, 2) void k_main(
        const int* __restrict__ sent, const int* __restrict__ qsent,
        const float* __restrict__ emb, unsigned* __restrict__ ghist) {
    __shared__ __align__(16) float dxT[HC][DTILE];   // 20 KB transposed tile
    __shared__ __align__(16) float qxT[HC][TQ];      // 2.5 KB
    __shared__ int      toks[DTILE];
    __shared__ int      qtk[TQ];
    __shared__ float    s_iq[TQ];
    __shared__ float    s_id[DTILE];
    __shared__ unsigned s_hist[TQ * NFEAT];

    const int b    = blockIdx.x >> 4;
    const int d0   = (blockIdx.x & 15) * DTILE;
    const int tid  = threadIdx.x;
    const int wid  = tid >> 6;
    const int lane = tid & 63;

    toks[tid] = sent[b * TD + d0 + tid];
    if (tid < TQ) qtk[tid] = qsent[b * TQ + tid];
    __syncthreads();

    // staging roles: thread t owns d-row t (and q-row t if t<32)
    const float* dptr = emb + (size_t)toks[tid] * HDIM;
    const bool   doq  = (tid < TQ);
    const float* qptr = emb + (size_t)(doq ? qtk[tid] : 0) * HDIM;

    float nd = 0.f, nq = 0.f;                // exact per-row norm accumulators

    // compute roles
    const int q0  = wid * 8;
    const int myd = lane * 4;

    // acc2[qp][di]: .x = q0+2*qp, .y = q0+2*qp+1, d = myd+di
    v2f acc2[4][4];
#pragma unroll
    for (int qp = 0; qp < 4; ++qp)
#pragma unroll
        for (int di = 0; di < 4; ++di) acc2[qp][di] = (v2f){0.f, 0.f};

    // ---- prefetch chunk 0 d-rows into registers
    float4 dreg[NF4];
#pragma unroll
    for (int jf = 0; jf < NF4; ++jf) dreg[jf] = *(const float4*)(dptr + jf * 4);

    for (int hc = 0; hc < NHC; ++hc) {
        // ---- q rows: direct load (issue first; latency hides under d writes below)
        float4 qv0, qv1, qv2, qv3, qv4;
        if (doq) {
            const float* pq = qptr + hc * HC;
            qv0 = *(const float4*)(pq);      qv1 = *(const float4*)(pq + 4);
            qv2 = *(const float4*)(pq + 8);  qv3 = *(const float4*)(pq + 12);
            qv4 = *(const float4*)(pq + 16);
        }

        // ---- write prefetched d-rows: column writes, lanes = consecutive rows (2-way, free)
#pragma unroll
        for (int jf = 0; jf < NF4; ++jf) {
            float4 v = dreg[jf];
            const int h = jf * 4;
            dxT[h + 0][tid] = v.x; dxT[h + 1][tid] = v.y;
            dxT[h + 2][tid] = v.z; dxT[h + 3][tid] = v.w;
            nd = fmaf(v.x, v.x, nd); nd = fmaf(v.y, v.y, nd);
            nd = fmaf(v.z, v.z, nd); nd = fmaf(v.w, v.w, nd);
        }
        // ---- prefetch next chunk's d-rows (in flight across the compute phase)
        if (hc + 1 < NHC) {
            const float* p = dptr + (hc + 1) * HC;
#pragma unroll
            for (int jf = 0; jf < NF4; ++jf) dreg[jf] = *(const float4*)(p + jf * 4);
        }
        // ---- write q rows
        if (doq) {
            float4 v;
            v = qv0; qxT[0][tid] = v.x; qxT[1][tid] = v.y; qxT[2][tid] = v.z; qxT[3][tid] = v.w;
            nq = fmaf(v.x, v.x, nq); nq = fmaf(v.y, v.y, nq); nq = fmaf(v.z, v.z, nq); nq = fmaf(v.w, v.w, nq);
            v = qv1; qxT[4][tid] = v.x; qxT[5][tid] = v.y; qxT[6][tid] = v.z; qxT[7][tid] = v.w;
            nq = fmaf(v.x, v.x, nq); nq = fmaf(v.y, v.y, nq); nq = fmaf(v.z, v.z, nq); nq = fmaf(v.w, v.w, nq);
            v = qv2; qxT[8][tid] = v.x; qxT[9][tid] = v.y; qxT[10][tid] = v.z; qxT[11][tid] = v.w;
            nq = fmaf(v.x, v.x, nq); nq = fmaf(v.y, v.y, nq); nq = fmaf(v.z, v.z, nq); nq = fmaf(v.w, v.w, nq);
            v = qv3; qxT[12][tid] = v.x; qxT[13][tid] = v.y; qxT[14][tid] = v.z; qxT[15][tid] = v.w;
            nq = fmaf(v.x, v.x, nq); nq = fmaf(v.y, v.y, nq); nq = fmaf(v.z, v.z, nq); nq = fmaf(v.w, v.w, nq);
            v = qv4; qxT[16][tid] = v.x; qxT[17][tid] = v.y; qxT[18][tid] = v.z; qxT[19][tid] = v.w;
            nq = fmaf(v.x, v.x, nq); nq = fmaf(v.y, v.y, nq); nq = fmaf(v.z, v.z, nq); nq = fmaf(v.w, v.w, nq);
        }
        __syncthreads();

        // ---- compute: per h: 1 lane-contiguous b128 (dx) + 2 uniform b128 (qx),
        //      16 v_pk_fma_f32 (32 fp32 FMA)
#pragma unroll
        for (int h = 0; h < HC; ++h) {
            float4 dv = *(const float4*)&dxT[h][myd];
            float4 a  = *(const float4*)&qxT[h][q0];
            float4 c  = *(const float4*)&qxT[h][q0 + 4];
            v2f a01 = {a.x, a.y}, a23 = {a.z, a.w};
            v2f c01 = {c.x, c.y}, c23 = {c.z, c.w};
            v2f dx0 = {dv.x, dv.x}, dx1 = {dv.y, dv.y};
            v2f dx2 = {dv.z, dv.z}, dx3 = {dv.w, dv.w};
            acc2[0][0] = FMA2(a01, dx0, acc2[0][0]); acc2[0][1] = FMA2(a01, dx1, acc2[0][1]);
            acc2[0][2] = FMA2(a01, dx2, acc2[0][2]); acc2[0][3] = FMA2(a01, dx3, acc2[0][3]);
            acc2[1][0] = FMA2(a23, dx0, acc2[1][0]); acc2[1][1] = FMA2(a23, dx1, acc2[1][1]);
            acc2[1][2] = FMA2(a23, dx2, acc2[1][2]); acc2[1][3] = FMA2(a23, dx3, acc2[1][3]);
            acc2[2][0] = FMA2(c01, dx0, acc2[2][0]); acc2[2][1] = FMA2(c01, dx1, acc2[2][1]);
            acc2[2][2] = FMA2(c01, dx2, acc2[2][2]); acc2[2][3] = FMA2(c01, dx3, acc2[2][3]);
            acc2[3][0] = FMA2(c23, dx0, acc2[3][0]); acc2[3][1] = FMA2(c23, dx1, acc2[3][1]);
            acc2[3][2] = FMA2(c23, dx2, acc2[3][2]); acc2[3][3] = FMA2(c23, dx3, acc2[3][3]);
        }
        __syncthreads();   // before next chunk overwrites dxT/qxT
    }

    // ---- finalize norms (exact single-register sums), init hist
    s_id[tid] = 1.0f / (sqrtf(nd + 1e-7f) + 1e-7f);
    if (doq) s_iq[tid] = 1.0f / (sqrtf(nq + 1e-7f) + 1e-7f);
    for (int i = tid; i < TQ * NFEAT; i += THREADS) s_hist[i] = 0u;
    __syncthreads();

    // ---- epilogue: sim -> bins (fully unrolled: acc stays in registers)
    {
        float id[4];
        bool  vd[4];
#pragma unroll
        for (int di = 0; di < 4; ++di) {
            id[di] = s_id[myd + di];
            vd[di] = (toks[myd + di] != 0);   // masked doc: +1e7 -> dropped everywhere
        }
#pragma unroll
        for (int qp = 0; qp < 4; ++qp) {
            const int qe = q0 + 2 * qp;
            const float iqe = s_iq[qe];
            const float iqo = s_iq[qe + 1];
#pragma unroll
            for (int di = 0; di < 4; ++di) {
                if (vd[di]) {
                    bin_one(acc2[qp][di].x * iqe * id[di], s_hist, qe);
                    bin_one(acc2[qp][di].y * iqo * id[di], s_hist, qe + 1);
                }
            }
        }
    }
    __syncthreads();
    for (int i = tid; i < TQ * NFEAT; i += THREADS) {
        unsigned v = s_hist[i];
        if (v) atomicAdd(&ghist[b * TQ * NFEAT + i], v);
    }
}

// ---------------- finish: log + MLP + gate softmax ----------------
__global__ void k_finish(const unsigned* __restrict__ ghist,
                         const int* __restrict__ qsent, const float* __restrict__ idf,
                         const float* __restrict__ w1, const float* __restrict__ b1,
                         const float* __restrict__ w2, const float* __restrict__ b2,
                         const float* __restrict__ gw, const float* __restrict__ ow,
                         const float* __restrict__ ob, float* __restrict__ out) {
    int b = blockIdx.x;
    int lane = threadIdx.x;   // 64 threads, lanes 0..31 active
    float ffw = 0.f;
    float logit = -3.0e38f;
    if (lane < TQ) {
        const unsigned* h = ghist + (b * TQ + lane) * NFEAT;
        float f[NFEAT];
        for (int k = 0; k < NFEAT; ++k) f[k] = logf((float)h[k] + 1.0f);
        float s2 = b2[0];
        for (int n = 0; n < 5; ++n) {
            float s = b1[n];
            for (int k = 0; k < NFEAT; ++k) s = fmaf(f[k], w1[k * 5 + n], s);
            s2 = fmaf(tanhf(s), w2[n], s2);
        }
        ffw = tanhf(s2);
        int qt = qsent[b * TQ + lane];
        logit = idf[b * TQ + lane] * gw[0] + (qt == 0 ? -1e7f : 0.f);
    }
    float m = logit;
#pragma unroll
    for (int t = 1; t < 64; t <<= 1) m = fmaxf(m, __shfl_xor(m, t, 64));
    float e = expf(logit - m);            // inactive lanes -> exp(-inf) = 0
    float se = e, sw = e * ffw;
#pragma unroll
    for (int t = 1; t < 64; t <<= 1) {
        se += __shfl_xor(se, t, 64);
        sw += __shfl_xor(sw, t, 64);
    }
    if (lane == 0) out[b] = (sw / se) * ow[0] + ob[0];
}

extern "C" void kernel_launch(void* const* d_in, const int* in_sizes, int n_in,
                              void* d_out, int out_size, void* d_ws, size_t ws_size,
                              hipStream_t stream) {
    const int*   sent  = (const int*)d_in[0];
    const int*   qsent = (const int*)d_in[1];
    const float* idf   = (const float*)d_in[2];
    const float* emb   = (const float*)d_in[3];
    const float* w1    = (const float*)d_in[4];
    const float* b1    = (const float*)d_in[5];
    const float* w2    = (const float*)d_in[6];
    const float* b2    = (const float*)d_in[7];
    const float* gw    = (const float*)d_in[8];
    const float* ow    = (const float*)d_in[9];
    const float* ob    = (const float*)d_in[10];
    float* out = (float*)d_out;

    unsigned* ghist = (unsigned*)d_ws;                 // 64*32*30 u32 = 240 KB

    hipMemsetAsync(ghist, 0, (size_t)B_ * TQ * NFEAT * 4, stream);
    k_main<<<B_ * NCHUNK, THREADS, 0, stream>>>(sent, qsent, emb, ghist);
    k_finish<<<B_, 64, 0, stream>>>(ghist, qsent, idf, w1, b1, w2, b2, gw, ow, ob, out);
}

// Round 8
// 127.551 us; speedup vs baseline: 2.3856x; 1.1469x over previous
//
#include <hip/hip_runtime.h>
#include <hip/hip_bf16.h>
#include <math.h>

#define B_    64
#define TQ    32
#define TD    4096
#define HDIM  300
#define NB    29      // histogram bins
#define NFEAT 30      // 29 bins + exact-match feature
#define DTILE 256
#define NCHUNK 16     // TD / DTILE
#define KPAD  320     // K padded to 4 chunks x 80
#define KC    80      // k per chunk = 5 ktiles of 16
#define NKC   4       // KPAD / KC
#define KT    5       // ktiles per chunk
#define THREADS 256

typedef _Float16 half4 __attribute__((ext_vector_type(4)));
typedef float    f32x4 __attribute__((ext_vector_type(4)));

// bin upper bounds: jnp.linspace(-1,1,30)[1:], ub[k] = -1 + 2(k+1)/29
__device__ __forceinline__ float ubf(int k) {
    return (float)(-1.0 + (2.0 * (double)(k + 1)) / 29.0);
}

// bin one similarity value into the per-block LDS histogram
__device__ __forceinline__ void bin_one(float sim, unsigned* s_hist, int q) {
    if (sim > 0.999f && sim < 1.001f) {
        // only exact token matches land here; true sim < 1.0 strictly -> bin 28
        atomicAdd(&s_hist[q * NFEAT + 28], 1u);
        atomicAdd(&s_hist[q * NFEAT + 29], 1u);   // exact-match feature
    } else {
        int idx = (int)((sim + 1.0f) * 14.5f);    // guess, then exact fixup
        idx = idx < 0 ? 0 : (idx > NB ? NB : idx);
        while (idx < NB && sim >= ubf(idx)) ++idx;
        while (idx > 0 && sim < ubf(idx - 1)) --idx;
        if (idx < NB) atomicAdd(&s_hist[q * NFEAT + idx], 1u);
    }
}

// ---------------- main: fused norms + fp16-MFMA sim + histogram ----------------
// 256 threads = 4 waves; tile 32q x 256d per block; K chunked 4 x 80 (5 ktiles).
// sim dot via v_mfma_f32_16x16x16f16 (canonical gfx908+ fragment layout):
//   A lane l: A[l%16][(l/16)*4+j]   B lane l: B[(l/16)*4+j][l%16]
//   D lane l: D[(l/16)*4+r][l%16]
// Staging thread t owns d-row t (q-row t too if t<32): loads f32 float4,
// accumulates exact fp32 norm (same order as r7 -> identical s_id/s_iq),
// converts to f16 and ds_write_b64 directly in fragment-major layout:
//   slot(kt, tile, lane) = ((kt*NT + tile)*64 + lane), 8B each; for a d-row r,
//   float4 jf (kt=jf>>2, g=jf&3) lands at lane (r&15)+16*g, tile r>>4.
// Compute reads are per-lane-contiguous ds_read_b64 (conflict-free).
// fp16 input rounding shifts sim by ~4e-5: ~8 bin flips per (b,q) row ->
// ~3e-7 output error (threshold 9e-6). Norms fp32 = reference. Exact-match
// window unaffected (sim = 1 +- 6e-5 for identical tokens).
// VGPR-cap empirics on this hipcc: (N,2) -> 128-VGPR cap, no spills (r4/r6/r7).
__global__ __launch_bounds__(THREADS, 2) void k_main(
        const int* __restrict__ sent, const int* __restrict__ qsent,
        const float* __restrict__ emb, unsigned* __restrict__ ghist) {
    __shared__ __align__(16) _Float16 bfr[KT * 16 * 64 * 4];  // 40 KB B-frags (d)
    __shared__ __align__(16) _Float16 afr[KT * 2  * 64 * 4];  // 5 KB  A-frags (q)
    __shared__ int      toks[DTILE];
    __shared__ int      qtk[TQ];
    __shared__ float    s_iq[TQ];
    __shared__ float    s_id[DTILE];
    __shared__ unsigned s_hist[TQ * NFEAT];

    const int b    = blockIdx.x >> 4;
    const int d0   = (blockIdx.x & 15) * DTILE;
    const int tid  = threadIdx.x;
    const int wid  = tid >> 6;
    const int lane = tid & 63;

    toks[tid] = sent[b * TD + d0 + tid];
    if (tid < TQ) qtk[tid] = qsent[b * TQ + tid];
    __syncthreads();

    // staging roles: thread t owns d-row t (and q-row t if t<32)
    const float* dptr = emb + (size_t)toks[tid] * HDIM;
    const bool   doq  = (tid < TQ);
    const float* qptr = emb + (size_t)(doq ? qtk[tid] : 0) * HDIM;
    const int tile_d  = tid >> 4;          // 0..15
    const int l16     = tid & 15;

    float nd = 0.f, nq = 0.f;              // exact fp32 norm accumulators

    f32x4 acc[2][4];                       // [mtile][ntile], 32 VGPRs
#pragma unroll
    for (int mt = 0; mt < 2; ++mt)
#pragma unroll
        for (int nt = 0; nt < 4; ++nt) acc[mt][nt] = (f32x4){0.f, 0.f, 0.f, 0.f};

    for (int c = 0; c < NKC; ++c) {
        const int kbase = c * KC;
        // ---- stage d-row: 20 float4 -> f16 frags (k>=300 zero-padded)
#pragma unroll
        for (int jf = 0; jf < 20; ++jf) {
            const int kglob = kbase + jf * 4;      // uniform per iteration
            float4 v = make_float4(0.f, 0.f, 0.f, 0.f);
            if (kglob < HDIM) v = *(const float4*)(dptr + kglob);
            nd = fmaf(v.x, v.x, nd); nd = fmaf(v.y, v.y, nd);
            nd = fmaf(v.z, v.z, nd); nd = fmaf(v.w, v.w, nd);
            half4 h = {(_Float16)v.x, (_Float16)v.y, (_Float16)v.z, (_Float16)v.w};
            const int kt = jf >> 2, g = jf & 3;
            *(half4*)&bfr[(((kt * 16 + tile_d) * 64) + l16 + 16 * g) * 4] = h;
        }
        // ---- stage q-row (threads < 32; tile = tid>>4 in {0,1})
        if (doq) {
#pragma unroll
            for (int jf = 0; jf < 20; ++jf) {
                const int kglob = kbase + jf * 4;
                float4 v = make_float4(0.f, 0.f, 0.f, 0.f);
                if (kglob < HDIM) v = *(const float4*)(qptr + kglob);
                nq = fmaf(v.x, v.x, nq); nq = fmaf(v.y, v.y, nq);
                nq = fmaf(v.z, v.z, nq); nq = fmaf(v.w, v.w, nq);
                half4 h = {(_Float16)v.x, (_Float16)v.y, (_Float16)v.z, (_Float16)v.w};
                const int kt = jf >> 2, g = jf & 3;
                *(half4*)&afr[(((kt * 2 + tile_d) * 64) + l16 + 16 * g) * 4] = h;
            }
        }
        __syncthreads();

        // ---- MFMA: wave w owns ntiles w*4..w*4+3, both mtiles
#pragma unroll
        for (int kt = 0; kt < KT; ++kt) {
            half4 a0 = *(const half4*)&afr[((kt * 2 + 0) * 64 + lane) * 4];
            half4 a1 = *(const half4*)&afr[((kt * 2 + 1) * 64 + lane) * 4];
#pragma unroll
            for (int nt = 0; nt < 4; ++nt) {
                half4 bv = *(const half4*)&bfr[((kt * 16 + wid * 4 + nt) * 64 + lane) * 4];
                acc[0][nt] = __builtin_amdgcn_mfma_f32_16x16x16f16(a0, bv, acc[0][nt], 0, 0, 0);
                acc[1][nt] = __builtin_amdgcn_mfma_f32_16x16x16f16(a1, bv, acc[1][nt], 0, 0, 0);
            }
        }
        __syncthreads();   // before next chunk overwrites frags
    }

    // ---- finalize norms (exact fp32, same order as r7), init hist
    s_id[tid] = 1.0f / (sqrtf(nd + 1e-7f) + 1e-7f);
    if (doq) s_iq[tid] = 1.0f / (sqrtf(nq + 1e-7f) + 1e-7f);
    for (int i = tid; i < TQ * NFEAT; i += THREADS) s_hist[i] = 0u;
    __syncthreads();

    // ---- epilogue: sim -> bins (fully static indexing)
    {
        const int qg = (lane >> 4) * 4;
#pragma unroll
        for (int nt = 0; nt < 4; ++nt) {
            const int d = (wid * 4 + nt) * 16 + (lane & 15);
            if (toks[d] == 0) continue;    // masked doc: +1e7 -> dropped everywhere
            const float idv = s_id[d];
#pragma unroll
            for (int mt = 0; mt < 2; ++mt) {
#pragma unroll
                for (int r = 0; r < 4; ++r) {
                    const int q = mt * 16 + qg + r;
                    bin_one(acc[mt][nt][r] * s_iq[q] * idv, s_hist, q);
                }
            }
        }
    }
    __syncthreads();
    for (int i = tid; i < TQ * NFEAT; i += THREADS) {
        unsigned v = s_hist[i];
        if (v) atomicAdd(&ghist[b * TQ * NFEAT + i], v);
    }
}

// ---------------- finish: log + MLP + gate softmax ----------------
__global__ void k_finish(const unsigned* __restrict__ ghist,
                         const int* __restrict__ qsent, const float* __restrict__ idf,
                         const float* __restrict__ w1, const float* __restrict__ b1,
                         const float* __restrict__ w2, const float* __restrict__ b2,
                         const float* __restrict__ gw, const float* __restrict__ ow,
                         const float* __restrict__ ob, float* __restrict__ out) {
    int b = blockIdx.x;
    int lane = threadIdx.x;   // 64 threads, lanes 0..31 active
    float ffw = 0.f;
    float logit = -3.0e38f;
    if (lane < TQ) {
        const unsigned* h = ghist + (b * TQ + lane) * NFEAT;
        float f[NFEAT];
        for (int k = 0; k < NFEAT; ++k) f[k] = logf((float)h[k] + 1.0f);
        float s2 = b2[0];
        for (int n = 0; n < 5; ++n) {
            float s = b1[n];
            for (int k = 0; k < NFEAT; ++k) s = fmaf(f[k], w1[k * 5 + n], s);
            s2 = fmaf(tanhf(s), w2[n], s2);
        }
        ffw = tanhf(s2);
        int qt = qsent[b * TQ + lane];
        logit = idf[b * TQ + lane] * gw[0] + (qt == 0 ? -1e7f : 0.f);
    }
    float m = logit;
#pragma unroll
    for (int t = 1; t < 64; t <<= 1) m = fmaxf(m, __shfl_xor(m, t, 64));
    float e = expf(logit - m);            // inactive lanes -> exp(-inf) = 0
    float se = e, sw = e * ffw;
#pragma unroll
    for (int t = 1; t < 64; t <<= 1) {
        se += __shfl_xor(se, t, 64);
        sw += __shfl_xor(sw, t, 64);
    }
    if (lane == 0) out[b] = (sw / se) * ow[0] + ob[0];
}

extern "C" void kernel_launch(void* const* d_in, const int* in_sizes, int n_in,
                              void* d_out, int out_size, void* d_ws, size_t ws_size,
                              hipStream_t stream) {
    const int*   sent  = (const int*)d_in[0];
    const int*   qsent = (const int*)d_in[1];
    const float* idf   = (const float*)d_in[2];
    const float* emb   = (const float*)d_in[3];
    const float* w1    = (const float*)d_in[4];
    const float* b1    = (const float*)d_in[5];
    const float* w2    = (const float*)d_in[6];
    const float* b2    = (const float*)d_in[7];
    const float* gw    = (const float*)d_in[8];
    const float* ow    = (const float*)d_in[9];
    const float* ob    = (const float*)d_in[10];
    float* out = (float*)d_out;

    unsigned* ghist = (unsigned*)d_ws;                 // 64*32*30 u32 = 240 KB

    hipMemsetAsync(ghist, 0, (size_t)B_ * TQ * NFEAT * 4, stream);
    k_main<<<B_ * NCHUNK, THREADS, 0, stream>>>(sent, qsent, emb, ghist);
    k_finish<<<B_, 64, 0, stream>>>(ghist, qsent, idf, w1, b1, w2, b2, gw, ow, ob, out);
}